// Round 13
// baseline (148.640 us; speedup 1.0000x reference)
//
#include <hip/hip_runtime.h>
#include <math.h>

#define FEAT 256
#define HID  16
#define STEPS 10

// d_ws ushort layout (written by prep each launch):
//   [0, 16384)      : AW  - Wih A-frags (32x32x16): [kc][gt][kt][lane][e], k sigma-permuted
//   [16384, 20480)  : PHI - phi A-frags (32x32x16): [ft][lane][e]
//   [20480, 21504)  : WHA - Whh A-frags (32x32x16): [gt][lane][e], k sigma-permuted
#define AW_N    16384
#define PHI_OFF 16384
#define PHI_N   4096
#define WHA_OFF 20480
#define WHA_N   1024
#define TOT_N   21504

typedef unsigned short ushort_t;
typedef __attribute__((ext_vector_type(8)))  short  short8;
typedef __attribute__((ext_vector_type(16))) float  floatx16;
typedef __attribute__((ext_vector_type(4)))  unsigned int uintx4;

__device__ __forceinline__ ushort_t f2bf_bits(float f) {
    union { float f; unsigned u; } cv; cv.f = f;
    unsigned u = cv.u;
    u = (u + 0x7FFFu + ((u >> 16) & 1u)) >> 16;   // RNE
    return (ushort_t)u;
}

__device__ __forceinline__ unsigned pk2bf(float lo, float hi) {
    unsigned r;
    asm("v_cvt_pk_bf16_f32 %0, %1, %2" : "=v"(r) : "v"(lo), "v"(hi));
    return r;
}

// relu two f32 then pack to bf16 pair.
// NOTE: int16-packed-relu (v_pk_max_i16 on bf16 bits) is BANNED - present in
// exactly the two NaN rounds (6, 11), absent from all passing rounds.
__device__ __forceinline__ unsigned relupk(float a, float b) {
    return pk2bf(fmaxf(a, 0.f), fmaxf(b, 0.f));
}

// split f32 into (hi_bf16, lo_bf16) packed dword
__device__ __forceinline__ unsigned packhl(float x) {
    unsigned u = __float_as_uint(x);
    float hi = __uint_as_float(u & 0xFFFF0000u);
    return pk2bf(hi, x - hi);
}

__device__ __forceinline__ short8 mk8(unsigned a, unsigned b, unsigned c, unsigned d) {
    union { unsigned u[4]; short8 s; } cv;
    cv.u[0] = a; cv.u[1] = b; cv.u[2] = c; cv.u[3] = d;
    return cv.s;
}

// sigma: the k-slot permutation the UNSWAPPED phi-D -> B-frag path induces.
// B slot [h2, e] holds feat/hidden sigma(h2,e); A-frags store the matching k.
__device__ __forceinline__ int sigma_k(int h2, int e) {
    return (e & 3) + 4 * h2 + 8 * (e >> 2);
}

// ---------------- prep: pack weight fragments (parallel) ----------------
__global__ void prep(const float* __restrict__ Wphi, const float* __restrict__ bphi,
                     const float* __restrict__ Wih,  const float* __restrict__ Whh,
                     void* __restrict__ ws) {
    int idx = blockIdx.x * 256 + threadIdx.x;
    const float L = 1.4426950408889634f;  // log2(e)
    ushort_t* p = (ushort_t*)ws;
    if (idx < AW_N) {
        // A[row=gate][k], lane holds row=gt*32+(l&31); k-slot [h2=(l>>5), e]
        // stores feat = kc*32 + kt*16 + sigma(h2,e)  (absorbs the data-side swap)
        int e    = idx & 7;
        int lane = (idx >> 3) & 63;
        int kt   = (idx >> 9) & 1;
        int gt   = (idx >> 10) & 1;
        int kc   = idx >> 11;
        int gate = gt * 32 + (lane & 31);
        int feat = kc * 32 + kt * 16 + sigma_k(lane >> 5, e);
        float sc = (gate >= 32 && gate < 48) ? (2.f * L) : L;   // g-gate: 2log2e
        p[idx] = f2bf_bits(Wih[gate * FEAT + feat] * sc);
    } else if (idx < WHA_OFF) {
        // phi A-frag: A[row=feat][k], k multiplies [w0h,w0l,w1h,w1l,w2h,w2l,1,0]
        int j    = idx - PHI_OFF;
        int e    = j & 7;
        int lane = (j >> 3) & 63;
        int ft   = j >> 9;
        float v = 0.f;
        if (lane < 32) {
            int f = ft * 32 + (lane & 31);
            if (e < 6)       v = Wphi[(e >> 1) * FEAT + f];
            else if (e == 6) v = bphi[f];
        }
        p[idx] = f2bf_bits(v);
    } else if (idx < TOT_N) {
        // Whh A-frag: A[row=gate][k=hidden], k-slot sigma-permuted (matches hB pack)
        int j    = idx - WHA_OFF;
        int e    = j & 7;
        int lane = (j >> 3) & 63;
        int gt   = j >> 9;
        int gate = gt * 32 + (lane & 31);
        int k    = sigma_k(lane >> 5, e);
        float sc = (gate >= 32 && gate < 48) ? (2.f * L) : L;
        p[idx] = f2bf_bits(Whh[gate * HID + k] * sc);
    }
}

// ---------------- main kernel: 32 rays/wave ----------------
// (256,4): grid = 4 blocks/CU -> ALL resident, no lone-block tail.
// Round-12 kernel needs only 80 VGPR (plswaps gone), fits the 128 cap.
// Gate: WRITE_SIZE must stay ~2048 KB (no spill) - else revert to (256,3).
__global__ __launch_bounds__(256, 4) void march(
    const float* __restrict__ c2w, const float* __restrict__ intr,
    const float* __restrict__ uv,  const float* __restrict__ dep0,
    const void* __restrict__ ws,
    const float* __restrict__ bih, const float* __restrict__ bhh,
    const float* __restrict__ Wout, const float* __restrict__ bout,
    float* __restrict__ out, int B, int N) {

    __shared__ __align__(16) ushort_t Slds[AW_N];   // 32 KB

    int tid = threadIdx.x;
    int wv = tid >> 6, l = tid & 63;
    int l31 = l & 31;
    bool hi32 = (l >= 32);
    int ray = blockIdx.x * 128 + wv * 32 + l31;   // lanes l and l+32 co-own ray
    int BN = B * N;
    int b = ray / N;

    const float L = 1.4426950408889634f;

    // stage Wih A-fragments into LDS (coalesced, conflict-free)
    {
        const uintx4* src = (const uintx4*)ws;
        uintx4* dst = (uintx4*)Slds;
        for (int i = tid; i < AW_N / 8; i += 256) dst[i] = src[i];
    }
    const short8* aw8 = (const short8*)Slds;
    const short8* phi8 = (const short8*)((const ushort_t*)ws + PHI_OFF);  // L1-resident

    // Whh A-frags from global (one-time)
    short8 whA0, whA1;
    {
        const short8* wha = (const short8*)((const ushort_t*)ws + WHA_OFF);
        whA0 = wha[l];
        whA1 = wha[64 + l];
    }

    // per-lane Wout slice: hid(q) = sigma(hi32, q)
    float wjv[8];
#pragma unroll
    for (int q = 0; q < 8; ++q) wjv[q] = Wout[(q & 3) + 4 * (int)hi32 + 8 * (q >> 2)];
    float bo = bout[0];

    // gate biases in C/D layout (f32, pre-scaled)
    floatx16 gb0, gb1;
#pragma unroll
    for (int r = 0; r < 16; ++r) {
        int loc = (r & 3) + 8 * (r >> 2) + 4 * (int)hi32;
        gb0[r] = L * (bih[loc] + bhh[loc]);                 // gates 0-31 (i,f)
        float sc1 = (r < 8) ? (2.f * L) : L;                // 32-47 g, 48-63 o
        gb1[r] = sc1 * (bih[32 + loc] + bhh[32 + loc]);
    }

    // ray geometry (lanes lo & hi both track the same ray)
    const float* M = c2w + b * 16;
    float R00 = M[0], R01 = M[1], R02 = M[2], t0 = M[3];
    float R10 = M[4], R11 = M[5], R12 = M[6], t1 = M[7];
    float R20 = M[8], R21 = M[9], R22 = M[10], t2 = M[11];
    const float* Kc = intr + b * 9;
    float fx = Kc[0], cx = Kc[2], fy = Kc[4], cy = Kc[5];

    float u = uv[ray * 2 + 0];
    float v = uv[ray * 2 + 1];
    float d0 = dep0[ray];

    float xl = (u - cx) / fx;
    float yl = (v - cy) / fy;
    float dx = R00 * xl + R01 * yl + R02;
    float dy = R10 * xl + R11 * yl + R12;
    float dz = R20 * xl + R21 * yl + R22;
    float invn = rsqrtf(dx * dx + dy * dy + dz * dz);
    float rdx = dx * invn, rdy = dy * invn, rdz = dz * invn;
    float w0 = fmaf(dx, d0, t0);
    float w1 = fmaf(dy, d0, t1);
    float w2 = fmaf(dz, d0, t2);

    short8 z8 = {0, 0, 0, 0, 0, 0, 0, 0};
    short8 hB = z8;                 // h_{s-1} B-frag (sigma-ordered)

    float cst[8];                   // c-state for this lane's 8 hidden dims
#pragma unroll
    for (int j = 0; j < 8; ++j) cst[j] = 0.f;

    __syncthreads();  // Slds staged

#pragma unroll 1
    for (int s = 0; s < STEPS; ++s) {
        // ---- world B-fragment (32x32x16), hi/lo bf16 split; hi lanes = k 8-15 = 0
        short8 bw;
        {
            unsigned a0 = hi32 ? 0u : packhl(w0);
            unsigned a1 = hi32 ? 0u : packhl(w1);
            unsigned a2 = hi32 ? 0u : packhl(w2);
            unsigned a3 = hi32 ? 0u : 0x00003F80u;
            bw = mk8(a0, a1, a2, a3);
        }

        floatx16 a0 = gb0, a1 = gb1;
        floatx16 zz = (floatx16){0.f,0.f,0.f,0.f,0.f,0.f,0.f,0.f,
                                 0.f,0.f,0.f,0.f,0.f,0.f,0.f,0.f};

        // ---- 8 feature chunks: phi MFMA -> relu/pack -> gates MFMA (no swaps:
        //      the sigma k-permutation lives in the prep-packed A-fragments)
#pragma unroll
        for (int kc = 0; kc < 8; ++kc) {
            short8 aphi = phi8[kc * 64 + l];
            floatx16 p = __builtin_amdgcn_mfma_f32_32x32x16_bf16(aphi, bw, zz, 0, 0, 0);

            unsigned P[8];
#pragma unroll
            for (int q = 0; q < 8; ++q)
                P[q] = relupk(p[2 * q], p[2 * q + 1]);
            short8 b0 = mk8(P[0], P[1], P[2], P[3]);   // k-slots 0-7  (sigma order)
            short8 b1 = mk8(P[4], P[5], P[6], P[7]);   // k-slots 8-15 (sigma order)

            short8 wA00 = aw8[(kc * 4 + 0) * 64 + l];  // gt0 kt0
            short8 wA01 = aw8[(kc * 4 + 1) * 64 + l];  // gt0 kt1
            short8 wA10 = aw8[(kc * 4 + 2) * 64 + l];  // gt1 kt0
            short8 wA11 = aw8[(kc * 4 + 3) * 64 + l];  // gt1 kt1

            a0 = __builtin_amdgcn_mfma_f32_32x32x16_bf16(wA00, b0, a0, 0, 0, 0);
            a0 = __builtin_amdgcn_mfma_f32_32x32x16_bf16(wA01, b1, a0, 0, 0, 0);
            a1 = __builtin_amdgcn_mfma_f32_32x32x16_bf16(wA10, b0, a1, 0, 0, 0);
            a1 = __builtin_amdgcn_mfma_f32_32x32x16_bf16(wA11, b1, a1, 0, 0, 0);
        }

        // ---- recurrence: gates += h_{s-1} @ Whh^T (sigma-consistent) ----
        a0 = __builtin_amdgcn_mfma_f32_32x32x16_bf16(whA0, hB, a0, 0, 0, 0);
        a1 = __builtin_amdgcn_mfma_f32_32x32x16_bf16(whA1, hB, a1, 0, 0, 0);

        // ---- LSTM elementwise: lane owns 8 hidden dims of ray l31 ----
        const float L2 = 2.8853900817779268f;  // 2*log2(e)
        float h0[8];
#pragma unroll
        for (int q = 0; q < 8; ++q) {
            float ig = __builtin_amdgcn_rcpf(1.f + __builtin_amdgcn_exp2f(-a0[q]));
            float fg = __builtin_amdgcn_rcpf(1.f + __builtin_amdgcn_exp2f(-a0[8 + q]));
            float gg = fmaf(-2.f, __builtin_amdgcn_rcpf(1.f + __builtin_amdgcn_exp2f(a1[q])), 1.f);
            float og = __builtin_amdgcn_rcpf(1.f + __builtin_amdgcn_exp2f(-a1[8 + q]));
            float cn = fmaf(fg, cst[q], ig * gg);
            cst[q] = cn;
            float tc = fmaf(-2.f, __builtin_amdgcn_rcpf(1.f + __builtin_amdgcn_exp2f(L2 * cn)), 1.f);
            h0[q] = og * tc;
        }

        // ---- sd = h . Wout : per-lane partial (8 dims) + one xor-32 add ----
        float sd = 0.f;
#pragma unroll
        for (int q = 0; q < 8; ++q) sd = fmaf(h0[q], wjv[q], sd);
        sd += __shfl_xor(sd, 32, 64);
        float sdv = sd + bo;

        // ---- pack h -> B-frag for next step (sigma order, no swaps) ----
        hB = mk8(pk2bf(h0[0], h0[1]), pk2bf(h0[2], h0[3]),
                 pk2bf(h0[4], h0[5]), pk2bf(h0[6], h0[7]));

        w0 = fmaf(rdx, sdv, w0);
        w1 = fmaf(rdy, sdv, w1);
        w2 = fmaf(rdz, sdv, w2);
    }

    if (!hi32) {
        int base = ray * 3;
        out[base + 0] = w0;
        out[base + 1] = w1;
        out[base + 2] = w2;
        float dd = R02 * (w0 - t0) + R12 * (w1 - t1) + R22 * (w2 - t2);
        out[BN * 3 + ray] = dd;
    }
}

extern "C" void kernel_launch(void* const* d_in, const int* in_sizes, int n_in,
                              void* d_out, int out_size, void* d_ws, size_t ws_size,
                              hipStream_t stream) {
    const float* c2w  = (const float*)d_in[0];
    const float* intr = (const float*)d_in[1];
    const float* uv   = (const float*)d_in[2];
    const float* dep  = (const float*)d_in[3];
    const float* Wphi = (const float*)d_in[4];
    const float* bphi = (const float*)d_in[5];
    const float* Wih  = (const float*)d_in[6];
    const float* bih  = (const float*)d_in[7];
    const float* Whh  = (const float*)d_in[8];
    const float* bhh  = (const float*)d_in[9];
    const float* Wout = (const float*)d_in[10];
    const float* bout = (const float*)d_in[11];
    float* out = (float*)d_out;

    int B = in_sizes[0] / 16;
    int BN = in_sizes[3];
    int N = BN / B;
    int blocks = (BN + 127) / 128;

    prep<<<(TOT_N + 255) / 256, 256, 0, stream>>>(Wphi, bphi, Wih, Whh, d_ws);
    march<<<blocks, 256, 0, stream>>>(c2w, intr, uv, dep, d_ws,
                                      bih, bhh, Wout, bout, out, B, N);
}

// Round 14
// 137.996 us; speedup vs baseline: 1.0771x; 1.0771x over previous
//
#include <hip/hip_runtime.h>
#include <math.h>

#define FEAT 256
#define HID  16
#define STEPS 10

// d_ws ushort layout (written by prep each launch):
//   [0, 16384)      : AW  - Wih A-frags (32x32x16): [kc][gt][kt][lane][e], k sigma-permuted
//   [16384, 20480)  : PHI - phi A-frags (32x32x16): [ft][lane][e]
//   [20480, 21504)  : WHA - Whh A-frags (32x32x16): [gt][lane][e], k sigma-permuted
#define AW_N    16384
#define PHI_OFF 16384
#define PHI_N   4096
#define WHA_OFF 20480
#define WHA_N   1024
#define TOT_N   21504

typedef unsigned short ushort_t;
typedef __attribute__((ext_vector_type(2)))  float  float2v;
typedef __attribute__((ext_vector_type(8)))  short  short8;
typedef __attribute__((ext_vector_type(16))) float  floatx16;
typedef __attribute__((ext_vector_type(4)))  unsigned int uintx4;

__device__ __forceinline__ ushort_t f2bf_bits(float f) {
    union { float f; unsigned u; } cv; cv.f = f;
    unsigned u = cv.u;
    u = (u + 0x7FFFu + ((u >> 16) & 1u)) >> 16;   // RNE
    return (ushort_t)u;
}

__device__ __forceinline__ unsigned pk2bf(float lo, float hi) {
    unsigned r;
    asm("v_cvt_pk_bf16_f32 %0, %1, %2" : "=v"(r) : "v"(lo), "v"(hi));
    return r;
}

// relu two f32 then pack to bf16 pair.
// NOTE: int16-packed-relu (v_pk_max_i16 on bf16 bits) is BANNED - present in
// exactly the two NaN rounds (6, 11), absent from all passing rounds.
// v_pk_max_f32 does not exist on gfx950 (round-4 compile error).
__device__ __forceinline__ unsigned relupk(float a, float b) {
    return pk2bf(fmaxf(a, 0.f), fmaxf(b, 0.f));
}

// split f32 into (hi_bf16, lo_bf16) packed dword
__device__ __forceinline__ unsigned packhl(float x) {
    unsigned u = __float_as_uint(x);
    float hi = __uint_as_float(u & 0xFFFF0000u);
    return pk2bf(hi, x - hi);
}

__device__ __forceinline__ short8 mk8(unsigned a, unsigned b, unsigned c, unsigned d) {
    union { unsigned u[4]; short8 s; } cv;
    cv.u[0] = a; cv.u[1] = b; cv.u[2] = c; cv.u[3] = d;
    return cv.s;
}

// sigma: the k-slot permutation the UNSWAPPED phi-D -> B-frag path induces.
__device__ __forceinline__ int sigma_k(int h2, int e) {
    return (e & 3) + 4 * h2 + 8 * (e >> 2);
}

// ---------------- prep: pack weight fragments (parallel) ----------------
__global__ void prep(const float* __restrict__ Wphi, const float* __restrict__ bphi,
                     const float* __restrict__ Wih,  const float* __restrict__ Whh,
                     void* __restrict__ ws) {
    int idx = blockIdx.x * 256 + threadIdx.x;
    const float L = 1.4426950408889634f;  // log2(e)
    ushort_t* p = (ushort_t*)ws;
    if (idx < AW_N) {
        int e    = idx & 7;
        int lane = (idx >> 3) & 63;
        int kt   = (idx >> 9) & 1;
        int gt   = (idx >> 10) & 1;
        int kc   = idx >> 11;
        int gate = gt * 32 + (lane & 31);
        int feat = kc * 32 + kt * 16 + sigma_k(lane >> 5, e);
        float sc = (gate >= 32 && gate < 48) ? (2.f * L) : L;   // g-gate: 2log2e
        p[idx] = f2bf_bits(Wih[gate * FEAT + feat] * sc);
    } else if (idx < WHA_OFF) {
        int j    = idx - PHI_OFF;
        int e    = j & 7;
        int lane = (j >> 3) & 63;
        int ft   = j >> 9;
        float v = 0.f;
        if (lane < 32) {
            int f = ft * 32 + (lane & 31);
            if (e < 6)       v = Wphi[(e >> 1) * FEAT + f];
            else if (e == 6) v = bphi[f];
        }
        p[idx] = f2bf_bits(v);
    } else if (idx < TOT_N) {
        int j    = idx - WHA_OFF;
        int e    = j & 7;
        int lane = (j >> 3) & 63;
        int gt   = j >> 9;
        int gate = gt * 32 + (lane & 31);
        int k    = sigma_k(lane >> 5, e);
        float sc = (gate >= 32 && gate < 48) ? (2.f * L) : L;
        p[idx] = f2bf_bits(Whh[gate * HID + k] * sc);
    }
}

// ---------------- main kernel: 32 rays/wave ----------------
// (256,3) is the proven no-spill point; (256,4) spills (r9, r13: 64-reg
// granule + 26 MB scratch). Do not raise.
__global__ __launch_bounds__(256, 3) void march(
    const float* __restrict__ c2w, const float* __restrict__ intr,
    const float* __restrict__ uv,  const float* __restrict__ dep0,
    const void* __restrict__ ws,
    const float* __restrict__ bih, const float* __restrict__ bhh,
    const float* __restrict__ Wout, const float* __restrict__ bout,
    float* __restrict__ out, int B, int N) {

    __shared__ __align__(16) ushort_t Slds[AW_N];   // 32 KB

    int tid = threadIdx.x;
    int wv = tid >> 6, l = tid & 63;
    int l31 = l & 31;
    bool hi32 = (l >= 32);
    int ray = blockIdx.x * 128 + wv * 32 + l31;   // lanes l and l+32 co-own ray
    int BN = B * N;
    int b = ray / N;

    const float L = 1.4426950408889634f;

    // stage Wih A-fragments into LDS (coalesced, conflict-free)
    {
        const uintx4* src = (const uintx4*)ws;
        uintx4* dst = (uintx4*)Slds;
        for (int i = tid; i < AW_N / 8; i += 256) dst[i] = src[i];
    }
    const short8* aw8 = (const short8*)Slds;
    const short8* phi8 = (const short8*)((const ushort_t*)ws + PHI_OFF);  // L1-resident

    // Whh A-frags from global (one-time)
    short8 whA0, whA1;
    {
        const short8* wha = (const short8*)((const ushort_t*)ws + WHA_OFF);
        whA0 = wha[l];
        whA1 = wha[64 + l];
    }

    // per-lane Wout slice as float2 pairs: hid(q) = sigma(hi32, q)
    float2v wj2[4];
#pragma unroll
    for (int qp = 0; qp < 4; ++qp) {
        int q0 = 2 * qp, q1 = 2 * qp + 1;
        wj2[qp].x = Wout[(q0 & 3) + 4 * (int)hi32 + 8 * (q0 >> 2)];
        wj2[qp].y = Wout[(q1 & 3) + 4 * (int)hi32 + 8 * (q1 >> 2)];
    }
    float bo = bout[0];

    // gate biases in C/D layout (f32, pre-scaled)
    floatx16 gb0, gb1;
#pragma unroll
    for (int r = 0; r < 16; ++r) {
        int loc = (r & 3) + 8 * (r >> 2) + 4 * (int)hi32;
        gb0[r] = L * (bih[loc] + bhh[loc]);                 // gates 0-31 (i,f)
        float sc1 = (r < 8) ? (2.f * L) : L;                // 32-47 g, 48-63 o
        gb1[r] = sc1 * (bih[32 + loc] + bhh[32 + loc]);
    }

    // ray geometry (lanes lo & hi both track the same ray)
    const float* M = c2w + b * 16;
    float R00 = M[0], R01 = M[1], R02 = M[2], t0 = M[3];
    float R10 = M[4], R11 = M[5], R12 = M[6], t1 = M[7];
    float R20 = M[8], R21 = M[9], R22 = M[10], t2 = M[11];
    const float* Kc = intr + b * 9;
    float fx = Kc[0], cx = Kc[2], fy = Kc[4], cy = Kc[5];

    float u = uv[ray * 2 + 0];
    float v = uv[ray * 2 + 1];
    float d0 = dep0[ray];

    float xl = (u - cx) / fx;
    float yl = (v - cy) / fy;
    float dx = R00 * xl + R01 * yl + R02;
    float dy = R10 * xl + R11 * yl + R12;
    float dz = R20 * xl + R21 * yl + R22;
    float invn = rsqrtf(dx * dx + dy * dy + dz * dz);
    float rdx = dx * invn, rdy = dy * invn, rdz = dz * invn;
    float w0 = fmaf(dx, d0, t0);
    float w1 = fmaf(dy, d0, t1);
    float w2 = fmaf(dz, d0, t2);

    short8 z8 = {0, 0, 0, 0, 0, 0, 0, 0};
    short8 hB = z8;                 // h_{s-1} B-frag (sigma-ordered)

    float2v cst[4];                 // c-state pairs
#pragma unroll
    for (int j = 0; j < 4; ++j) { cst[j].x = 0.f; cst[j].y = 0.f; }

    __syncthreads();  // Slds staged

#pragma unroll 1
    for (int s = 0; s < STEPS; ++s) {
        // ---- world B-fragment (32x32x16), hi/lo bf16 split; hi lanes = k 8-15 = 0
        short8 bw;
        {
            unsigned a0i = hi32 ? 0u : packhl(w0);
            unsigned a1i = hi32 ? 0u : packhl(w1);
            unsigned a2i = hi32 ? 0u : packhl(w2);
            unsigned a3i = hi32 ? 0u : 0x00003F80u;
            bw = mk8(a0i, a1i, a2i, a3i);
        }

        floatx16 a0, a1;
        floatx16 zz = (floatx16){0.f,0.f,0.f,0.f,0.f,0.f,0.f,0.f,
                                 0.f,0.f,0.f,0.f,0.f,0.f,0.f,0.f};

        // ---- 8 feature chunks: phi MFMA -> relu/pack -> gates MFMA.
        //      kc==0 peels: bias regs gb0/gb1 are the C operand (no acc-init movs)
#pragma unroll
        for (int kc = 0; kc < 8; ++kc) {
            short8 aphi = phi8[kc * 64 + l];
            floatx16 p = __builtin_amdgcn_mfma_f32_32x32x16_bf16(aphi, bw, zz, 0, 0, 0);

            unsigned P[8];
#pragma unroll
            for (int q = 0; q < 8; ++q)
                P[q] = relupk(p[2 * q], p[2 * q + 1]);
            short8 b0 = mk8(P[0], P[1], P[2], P[3]);   // k-slots 0-7  (sigma order)
            short8 b1 = mk8(P[4], P[5], P[6], P[7]);   // k-slots 8-15 (sigma order)

            short8 wA00 = aw8[(kc * 4 + 0) * 64 + l];  // gt0 kt0
            short8 wA01 = aw8[(kc * 4 + 1) * 64 + l];  // gt0 kt1
            short8 wA10 = aw8[(kc * 4 + 2) * 64 + l];  // gt1 kt0
            short8 wA11 = aw8[(kc * 4 + 3) * 64 + l];  // gt1 kt1

            a0 = __builtin_amdgcn_mfma_f32_32x32x16_bf16(wA00, b0, (kc == 0) ? gb0 : a0, 0, 0, 0);
            a0 = __builtin_amdgcn_mfma_f32_32x32x16_bf16(wA01, b1, a0, 0, 0, 0);
            a1 = __builtin_amdgcn_mfma_f32_32x32x16_bf16(wA10, b0, (kc == 0) ? gb1 : a1, 0, 0, 0);
            a1 = __builtin_amdgcn_mfma_f32_32x32x16_bf16(wA11, b1, a1, 0, 0, 0);
        }

        // ---- recurrence: gates += h_{s-1} @ Whh^T (sigma-consistent) ----
        a0 = __builtin_amdgcn_mfma_f32_32x32x16_bf16(whA0, hB, a0, 0, 0, 0);
        a1 = __builtin_amdgcn_mfma_f32_32x32x16_bf16(whA1, hB, a1, 0, 0, 0);

        // ---- LSTM elementwise on float2 pairs (v_pk_add/fma/mul_f32) ----
        const float L2 = 2.8853900817779268f;  // 2*log2(e)
        const float2v one2 = {1.f, 1.f};
        const float2v m22  = {-2.f, -2.f};
        float2v hv[4];
        float2v sd2 = {0.f, 0.f};
#pragma unroll
        for (int qp = 0; qp < 4; ++qp) {
            int q = 2 * qp;
            float2v ei, ef, eg, eo;
            ei.x = __builtin_amdgcn_exp2f(-a0[q]);     ei.y = __builtin_amdgcn_exp2f(-a0[q + 1]);
            ef.x = __builtin_amdgcn_exp2f(-a0[8 + q]); ef.y = __builtin_amdgcn_exp2f(-a0[9 + q]);
            eg.x = __builtin_amdgcn_exp2f(a1[q]);      eg.y = __builtin_amdgcn_exp2f(a1[q + 1]);
            eo.x = __builtin_amdgcn_exp2f(-a1[8 + q]); eo.y = __builtin_amdgcn_exp2f(-a1[9 + q]);
            float2v di = one2 + ei, df = one2 + ef, dg = one2 + eg, dn = one2 + eo;
            float2v ig, fg, rg, og;
            ig.x = __builtin_amdgcn_rcpf(di.x); ig.y = __builtin_amdgcn_rcpf(di.y);
            fg.x = __builtin_amdgcn_rcpf(df.x); fg.y = __builtin_amdgcn_rcpf(df.y);
            rg.x = __builtin_amdgcn_rcpf(dg.x); rg.y = __builtin_amdgcn_rcpf(dg.y);
            og.x = __builtin_amdgcn_rcpf(dn.x); og.y = __builtin_amdgcn_rcpf(dn.y);
            float2v gg = m22 * rg + one2;              // tanh via sigmoid
            float2v cn = fg * cst[qp] + ig * gg;
            cst[qp] = cn;
            float2v ac; ac.x = L2 * cn.x; ac.y = L2 * cn.y;
            float2v ec;
            ec.x = __builtin_amdgcn_exp2f(ac.x); ec.y = __builtin_amdgcn_exp2f(ac.y);
            float2v dc = one2 + ec;
            float2v rc;
            rc.x = __builtin_amdgcn_rcpf(dc.x); rc.y = __builtin_amdgcn_rcpf(dc.y);
            float2v tc = m22 * rc + one2;
            float2v h2 = og * tc;
            hv[qp] = h2;
            sd2 = h2 * wj2[qp] + sd2;
        }

        // ---- sd reduce: pair-sum + one xor-32 add ----
        float sd = sd2.x + sd2.y;
        sd += __shfl_xor(sd, 32, 64);
        float sdv = sd + bo;

        // ---- pack h -> B-frag for next step (sigma order) ----
        hB = mk8(pk2bf(hv[0].x, hv[0].y), pk2bf(hv[1].x, hv[1].y),
                 pk2bf(hv[2].x, hv[2].y), pk2bf(hv[3].x, hv[3].y));

        w0 = fmaf(rdx, sdv, w0);
        w1 = fmaf(rdy, sdv, w1);
        w2 = fmaf(rdz, sdv, w2);
    }

    if (!hi32) {
        int base = ray * 3;
        out[base + 0] = w0;
        out[base + 1] = w1;
        out[base + 2] = w2;
        float dd = R02 * (w0 - t0) + R12 * (w1 - t1) + R22 * (w2 - t2);
        out[BN * 3 + ray] = dd;
    }
}

extern "C" void kernel_launch(void* const* d_in, const int* in_sizes, int n_in,
                              void* d_out, int out_size, void* d_ws, size_t ws_size,
                              hipStream_t stream) {
    const float* c2w  = (const float*)d_in[0];
    const float* intr = (const float*)d_in[1];
    const float* uv   = (const float*)d_in[2];
    const float* dep  = (const float*)d_in[3];
    const float* Wphi = (const float*)d_in[4];
    const float* bphi = (const float*)d_in[5];
    const float* Wih  = (const float*)d_in[6];
    const float* bih  = (const float*)d_in[7];
    const float* Whh  = (const float*)d_in[8];
    const float* bhh  = (const float*)d_in[9];
    const float* Wout = (const float*)d_in[10];
    const float* bout = (const float*)d_in[11];
    float* out = (float*)d_out;

    int B = in_sizes[0] / 16;
    int BN = in_sizes[3];
    int N = BN / B;
    int blocks = (BN + 127) / 128;

    prep<<<(TOT_N + 255) / 256, 256, 0, stream>>>(Wphi, bphi, Wih, Whh, d_ws);
    march<<<blocks, 256, 0, stream>>>(c2w, intr, uv, dep, d_ws,
                                      bih, bhh, Wout, bout, out, B, N);
}